// Round 13
// baseline (149.800 us; speedup 1.0000x reference)
//
#include <hip/hip_runtime.h>
#include <hip/hip_bf16.h>

#define LDIM 8192
#define HDIM 16
#define DDIM 64
#define NHEADPAIR 64          // N*H
#define ROWSTRIDE 1024        // H*D floats between consecutive l for fixed h
#define KVSZ 4160             // 64*64 KV + 64 ksum
#define EPSF 1e-6f
#define TROWS 32              // s-rows per staged tile
#define CHUNKS 32             // l-chunks per (n,h)
#define RPB 256               // rows per block = LDIM/CHUNKS
#define NT 8                  // RPB/TROWS

typedef float f32x4 __attribute__((ext_vector_type(4)));
typedef short s16x8 __attribute__((ext_vector_type(8)));   // 8 bf16 (4 VGPRs)

__device__ __forceinline__ float featmap(float x) {
    // elu(x)+1 : x>0 -> x+1 ; x<=0 -> exp(x)
    return x > 0.0f ? x + 1.0f : __expf(x);
}

__device__ __forceinline__ unsigned int pack_bf16x2(float a, float b) {
    union { __hip_bfloat162 h; unsigned int u; } x;
    x.h = __float22bfloat162_rn(make_float2(a, b));   // elem0 -> low 16 bits
    return x.u;
}

// swizzle: XOR bits 2-3 of the s-pair slot with d bits 3-4 (16B-align-preserving)
__device__ __forceinline__ int swz(int d) { return ((d >> 3) & 3) << 2; }

// ---------------- Phase 1 (MFMA, 4 heads/block): partial KV[d][m], Ksum[d] ----------
// Each block covers heads hq*4..hq*4+3 of one n over 256 rows: per row-pair it reads
// 1KB contiguous (4x denser than the 256B/4KB single-head pattern that measured
// ~1.6TB/s across three structures). Wave w computes head w entirely with the
// validated 16x16x32 frag/swizzle formulas (acc = 16 D-tiles + ksum).
__global__ __launch_bounds__(256) void kv_mfma_kernel(
    const float* __restrict__ Kp, const float* __restrict__ Vp,
    float* __restrict__ part)
{
    __shared__ unsigned int KT[2][4][1024];   // [buf][head][d*16 + swizzled s-pair]
    __shared__ unsigned int VT[2][4][1024];

    const int bq   = blockIdx.x;     // n*4 + hq
    const int n    = bq >> 2;
    const int hq   = bq & 3;
    const int ch   = blockIdx.y;
    const int t    = threadIdx.x;
    const int wave = t >> 6;
    const int lane = t & 63;

    // staging map (R12-validated, looped over 4 heads): t<128 stage K (+featmap),
    // t>=128 stage V. u&7 = 8-col group, u>>3 = s-pair within tile.
    const bool isK = (t < 128);
    const int  u   = t & 127;
    const int  dg  = u & 7;
    const int  rp  = u >> 3;
    const float* Sp = isK ? Kp : Vp;
    const size_t base0 = (((size_t)n * LDIM + (size_t)ch * RPB + 2 * rp) * ROWSTRIDE)
                       + hq * 256 + dg * 8;

    // compute-side frag coords (identical to validated kernel)
    const int fr = lane & 15;
    const int fk = lane >> 4;

    f32x4 acc[4][4];    // [d-band][m-band]
    f32x4 zac[4];       // ksum per d-band
#pragma unroll
    for (int b = 0; b < 4; ++b) {
        zac[b] = (f32x4){0.f, 0.f, 0.f, 0.f};
#pragma unroll
        for (int mb = 0; mb < 4; ++mb) acc[b][mb] = (f32x4){0.f, 0.f, 0.f, 0.f};
    }
    s16x8 ones;
#pragma unroll
    for (int i = 0; i < 8; ++i) ones[i] = (short)0x3F80;   // bf16 1.0

    float4 st[4][4];    // [head][row-even lo/hi, row-odd lo/hi]

    // ---- prologue: load + store tile 0 ----
#pragma unroll
    for (int hh = 0; hh < 4; ++hh) {
        const float* S = Sp + base0 + hh * 64;
        st[hh][0] = *(const float4*)(S);
        st[hh][1] = *(const float4*)(S + 4);
        st[hh][2] = *(const float4*)(S + ROWSTRIDE);
        st[hh][3] = *(const float4*)(S + ROWSTRIDE + 4);
    }
#pragma unroll
    for (int hh = 0; hh < 4; ++hh) {
        unsigned int* T = isK ? &KT[0][hh][0] : &VT[0][hh][0];
        const float* a = (const float*)&st[hh][0];   // even row, 8 floats
        const float* b = (const float*)&st[hh][2];   // odd row, 8 floats
#pragma unroll
        for (int j = 0; j < 8; ++j) {
            const int d = dg * 8 + j;
            float fe = a[j], fo = b[j];
            if (isK) { fe = featmap(fe); fo = featmap(fo); }
            T[d * 16 + (rp ^ swz(d))] = pack_bf16x2(fe, fo);
        }
    }
    __syncthreads();

    int buf = 0;
    for (int tt = 0; tt < NT; ++tt) {
        const bool more = (tt + 1 < NT);
        if (more) {
#pragma unroll
            for (int hh = 0; hh < 4; ++hh) {
                const float* S = Sp + base0
                               + (size_t)(tt + 1) * TROWS * ROWSTRIDE + hh * 64;
                st[hh][0] = *(const float4*)(S);
                st[hh][1] = *(const float4*)(S + 4);
                st[hh][2] = *(const float4*)(S + ROWSTRIDE);
                st[hh][3] = *(const float4*)(S + ROWSTRIDE + 4);
            }
        }

        // ---- compute tile tt: wave = head; 8 ds_read_b128 + 20 MFMAs ----
        {
            s16x8 A[4];
#pragma unroll
            for (int b = 0; b < 4; ++b) {
                const int d = b * 16 + fr;
                A[b] = *(const s16x8*)&KT[buf][wave][d * 16 + ((fk * 4) ^ swz(d))];
            }
#pragma unroll
            for (int b = 0; b < 4; ++b)
                zac[b] = __builtin_amdgcn_mfma_f32_16x16x32_bf16(A[b], ones, zac[b], 0, 0, 0);
#pragma unroll
            for (int mb = 0; mb < 4; ++mb) {
                const int m = mb * 16 + fr;
                s16x8 B = *(const s16x8*)&VT[buf][wave][m * 16 + ((fk * 4) ^ swz(m))];
#pragma unroll
                for (int b = 0; b < 4; ++b)
                    acc[b][mb] = __builtin_amdgcn_mfma_f32_16x16x32_bf16(A[b], B, acc[b][mb], 0, 0, 0);
            }
        }

        if (more) {
#pragma unroll
            for (int hh = 0; hh < 4; ++hh) {
                unsigned int* T = isK ? &KT[buf ^ 1][hh][0] : &VT[buf ^ 1][hh][0];
                const float* a = (const float*)&st[hh][0];
                const float* b = (const float*)&st[hh][2];
#pragma unroll
                for (int j = 0; j < 8; ++j) {
                    const int d = dg * 8 + j;
                    float fe = a[j], fo = b[j];
                    if (isK) { fe = featmap(fe); fo = featmap(fo); }
                    T[d * 16 + (rp ^ swz(d))] = pack_bf16x2(fe, fo);
                }
            }
        }
        __syncthreads();
        buf ^= 1;
    }

    // ---- epilogue: wave writes its head's full 64x64 partial + ksum ----
    const int nh = n * 16 + hq * 4 + wave;
    float* p = part + ((size_t)nh * CHUNKS + ch) * KVSZ;
#pragma unroll
    for (int b = 0; b < 4; ++b)
#pragma unroll
        for (int mb = 0; mb < 4; ++mb)
#pragma unroll
            for (int reg = 0; reg < 4; ++reg)
                p[(b * 16 + fk * 4 + reg) * 64 + mb * 16 + fr] = acc[b][mb][reg];
    if (fr == 0)
#pragma unroll
        for (int b = 0; b < 4; ++b)
#pragma unroll
            for (int reg = 0; reg < 4; ++reg)
                p[4096 + b * 16 + fk * 4 + reg] = zac[b][reg];
}

// ---------------- Phase 1b: reduce partials, emit bf16 KV + ksum --------------------
__global__ __launch_bounds__(256) void kv_reduce_kernel(
    const float* __restrict__ part, unsigned short* __restrict__ kvh)
{
    const int nh = blockIdx.y;
    const int e  = blockIdx.x * 256 + threadIdx.x;
    if (e >= KVSZ) return;
    float s = 0.0f;
    for (int c = 0; c < CHUNKS; ++c)
        s += part[((size_t)nh * CHUNKS + c) * KVSZ + e];
    union { __hip_bfloat16 h; unsigned short u; } cv;
    cv.h = __float2bfloat16(s);
    kvh[(size_t)nh * KVSZ + e] = cv.u;
}

// ---------------- Phase 2 (MFMA): out[l][m] = Z * sum_d fmQ[l][d] * KV[m][d] --------
// Unchanged (validated).
__global__ __launch_bounds__(256) void attn_mfma_kernel(
    const float* __restrict__ Qp, const unsigned short* __restrict__ kvh,
    float* __restrict__ out)
{
    __shared__ unsigned int kvU[64][36];
    __shared__ unsigned int ksU[36];
    __shared__ unsigned int qU[128][36];

    const int nh = blockIdx.y;
    const int n  = nh >> 4;
    const int h  = nh & 15;
    const int t  = threadIdx.x;

    {
        const unsigned int* kvg = (const unsigned int*)(kvh + (size_t)nh * KVSZ);
        const int r  = t >> 2;
        const int c0 = (t & 3) * 8;
        uint4 x = *(const uint4*)(kvg + r * 32 + c0);
        uint4 y = *(const uint4*)(kvg + r * 32 + c0 + 4);
        *(uint4*)&kvU[r][c0]     = x;
        *(uint4*)&kvU[r][c0 + 4] = y;
        if (t < 32) ksU[t] = kvg[2048 + t];
    }

    {
        const int qr = t >> 1;
        const float* qg = Qp + ((((size_t)n * LDIM) + (size_t)blockIdx.x * 128 + qr)
                                * HDIM + h) * DDIM + (t & 1) * 32;
        unsigned int q[16];
#pragma unroll
        for (int j = 0; j < 8; ++j) {
            float4 f = *(const float4*)(qg + j * 4);
            q[2 * j]     = pack_bf16x2(featmap(f.x), featmap(f.y));
            q[2 * j + 1] = pack_bf16x2(featmap(f.z), featmap(f.w));
        }
        uint4* dst = (uint4*)&qU[qr][(t & 1) * 16];
        dst[0] = make_uint4(q[0],  q[1],  q[2],  q[3]);
        dst[1] = make_uint4(q[4],  q[5],  q[6],  q[7]);
        dst[2] = make_uint4(q[8],  q[9],  q[10], q[11]);
        dst[3] = make_uint4(q[12], q[13], q[14], q[15]);
    }
    __syncthreads();

    const int wave = t >> 6;
    const int lane = t & 63;
    const int fr = lane & 15;
    const int fk = lane >> 4;

    s16x8 bF[4][2], kF[2];
#pragma unroll
    for (int mt = 0; mt < 4; ++mt)
#pragma unroll
        for (int kk = 0; kk < 2; ++kk)
            bF[mt][kk] = *(const s16x8*)&kvU[mt * 16 + fr][kk * 16 + fk * 4];
#pragma unroll
    for (int kk = 0; kk < 2; ++kk)
        kF[kk] = *(const s16x8*)&ksU[kk * 16 + fk * 4];

    f32x4 acc[2][4];
    f32x4 zac[2];
#pragma unroll
    for (int lt = 0; lt < 2; ++lt) {
        zac[lt] = (f32x4){0.f, 0.f, 0.f, 0.f};
#pragma unroll
        for (int mt = 0; mt < 4; ++mt) acc[lt][mt] = (f32x4){0.f, 0.f, 0.f, 0.f};
    }

#pragma unroll
    for (int kk = 0; kk < 2; ++kk) {
#pragma unroll
        for (int lt = 0; lt < 2; ++lt) {
            s16x8 A = *(const s16x8*)&qU[wave * 32 + lt * 16 + fr][kk * 16 + fk * 4];
            zac[lt] = __builtin_amdgcn_mfma_f32_16x16x32_bf16(A, kF[kk], zac[lt], 0, 0, 0);
#pragma unroll
            for (int mt = 0; mt < 4; ++mt)
                acc[lt][mt] = __builtin_amdgcn_mfma_f32_16x16x32_bf16(
                    A, bF[mt][kk], acc[lt][mt], 0, 0, 0);
        }
    }

#pragma unroll
    for (int lt = 0; lt < 2; ++lt) {
#pragma unroll
        for (int reg = 0; reg < 4; ++reg) {
            const int row = blockIdx.x * 128 + wave * 32 + lt * 16 + fk * 4 + reg;
            const float z = 1.0f / (zac[lt][reg] + EPSF);
            float* orow = out + (((size_t)n * LDIM + row) * HDIM + h) * DDIM;
#pragma unroll
            for (int mt = 0; mt < 4; ++mt)
                orow[mt * 16 + fr] = acc[lt][mt][reg] * z;
        }
    }
}

extern "C" void kernel_launch(void* const* d_in, const int* in_sizes, int n_in,
                              void* d_out, int out_size, void* d_ws, size_t ws_size,
                              hipStream_t stream) {
    const float* Q = (const float*)d_in[0];
    const float* K = (const float*)d_in[1];
    const float* V = (const float*)d_in[2];
    float* out = (float*)d_out;
    float* ws  = (float*)d_ws;

    float* part = ws;                                         // 64*32*4160*4 = 34 MB
    unsigned short* kvh = (unsigned short*)(ws + (size_t)NHEADPAIR * CHUNKS * KVSZ);

    dim3 g1(16, CHUNKS);                 // x = (n,hq) quads co-resident
    kv_mfma_kernel<<<g1, 256, 0, stream>>>(K, V, part);
    dim3 gr((KVSZ + 255) / 256, NHEADPAIR);
    kv_reduce_kernel<<<gr, 256, 0, stream>>>(part, kvh);
    dim3 g2(LDIM / 128, NHEADPAIR);
    attn_mfma_kernel<<<g2, 256, 0, stream>>>(Q, kvh, out);
}